// Round 1
// baseline (146.856 us; speedup 1.0000x reference)
//
#include <hip/hip_runtime.h>

// ---------------------------------------------------------------------------
// Attention block, MI355X bf16-MFMA implementation.
// Pipeline: cvt3 (fp32->bf16) -> qkv GEMM (m97-style) -> rope/scatter ->
//           flash attention (swapped QK^T, exp2 domain) -> proj GEMM.
// Workspace layout (~79.2 MB, all bf16):
//   x16[S*DIM] wq16[3D*D] wp16[D*D] qkv16[S*3D] Q[H*S*96] K[H*S*96]
//   VT[H*80*S] attn16[S*DIM]
// ---------------------------------------------------------------------------

typedef __bf16 bf16;
typedef __bf16 bf16x4 __attribute__((ext_vector_type(4)));
typedef __bf16 bf16x8 __attribute__((ext_vector_type(8)));
typedef float f32x4 __attribute__((ext_vector_type(4)));

constexpr int S = 3072;
constexpr int DIM = 1280;
constexpr int H = 16;
constexpr int HD = 80;
constexpr int DP = 96;          // padded head dim for QK (multiple of 32)
constexpr int NQKV = 3 * DIM;   // 3840

// log2(e) / sqrt(80): folded into Q so scores are in exp2 domain.
constexpr float QSCALE = 1.4426950408889634f / 8.94427190999916f;

__device__ __forceinline__ void gload_lds16(const void* g, void* l) {
  __builtin_amdgcn_global_load_lds(
      (const __attribute__((address_space(1))) void*)g,
      (__attribute__((address_space(3))) void*)l, 16, 0, 0);
}

// --------------------------- fp32 -> bf16 convert ---------------------------
constexpr long CN1 = (long)S * DIM;       // x
constexpr long CN2 = (long)NQKV * DIM;    // w_qkv
constexpr long CN3 = (long)DIM * DIM;     // w_proj

__global__ __launch_bounds__(256) void cvt3(
    const float* __restrict__ x, const float* __restrict__ wq,
    const float* __restrict__ wp, bf16* __restrict__ xo,
    bf16* __restrict__ wqo, bf16* __restrict__ wpo) {
  long i = ((long)blockIdx.x * 256 + threadIdx.x) * 4;
  const float* s;
  bf16* d;
  if (i < CN1) { s = x + i; d = xo + i; }
  else if (i < CN1 + CN2) { s = wq + (i - CN1); d = wqo + (i - CN1); }
  else { s = wp + (i - CN1 - CN2); d = wpo + (i - CN1 - CN2); }
  float4 v = *(const float4*)s;
  bf16x4 o = {(bf16)v.x, (bf16)v.y, (bf16)v.z, (bf16)v.w};
  *(bf16x4*)d = o;
}

// --------------------------- GEMM (A row-major, B^T rows) -------------------
// C[m][n] = sum_k A[m][k]*B[n][k] + bias[n].  128x128 tile, BK=32, 4 waves.
template <bool OUT_BF16>
__global__ __launch_bounds__(256) void gemm_bt(
    const bf16* __restrict__ A, const bf16* __restrict__ B,
    const float* __restrict__ bias, void* __restrict__ Cout, int M, int N,
    int K) {
  __shared__ bf16 Al[128 * 32];
  __shared__ bf16 Bl[128 * 32];
  const int tid = threadIdx.x;
  const int w = tid >> 6, lane = tid & 63;
  const int r15 = lane & 15, b4 = lane >> 4;
  const int m0 = blockIdx.y * 128, n0 = blockIdx.x * 128;
  const int wm = (w >> 1) * 64, wn = (w & 1) * 64;
  f32x4 acc[4][4] = {};
  // staging: chunk c in [0,512): row=c>>2 (128 rows), 16B slot (c&3)
  const int row0 = tid >> 2, ko0 = (tid & 3) * 8;
  const bf16* Ar0 = A + (size_t)(m0 + row0) * K + ko0;
  const bf16* Ar1 = A + (size_t)(m0 + row0 + 64) * K + ko0;
  const bf16* Br0 = B + (size_t)(n0 + row0) * K + ko0;
  const bf16* Br1 = B + (size_t)(n0 + row0 + 64) * K + ko0;
  char* lA0 = (char*)Al + w * 1024;
  char* lA1 = (char*)Al + 4096 + w * 1024;
  char* lB0 = (char*)Bl + w * 1024;
  char* lB1 = (char*)Bl + 4096 + w * 1024;
  for (int k0 = 0; k0 < K; k0 += 32) {
    __syncthreads();
    gload_lds16(Ar0 + k0, lA0);
    gload_lds16(Ar1 + k0, lA1);
    gload_lds16(Br0 + k0, lB0);
    gload_lds16(Br1 + k0, lB1);
    __syncthreads();
    bf16x8 af[4], bfr[4];
#pragma unroll
    for (int i = 0; i < 4; i++) {
      af[i] = *(const bf16x8*)((const char*)Al + (wm + i * 16 + r15) * 64 + b4 * 16);
      bfr[i] = *(const bf16x8*)((const char*)Bl + (wn + i * 16 + r15) * 64 + b4 * 16);
    }
#pragma unroll
    for (int i = 0; i < 4; i++)
#pragma unroll
      for (int j = 0; j < 4; j++)
        acc[i][j] = __builtin_amdgcn_mfma_f32_16x16x32_bf16(af[i], bfr[j], acc[i][j], 0, 0, 0);
  }
#pragma unroll
  for (int j = 0; j < 4; j++) {
    const int n = n0 + wn + j * 16 + r15;
    const float bv = bias[n];
#pragma unroll
    for (int i = 0; i < 4; i++) {
      const int mr = m0 + wm + i * 16 + b4 * 4;
#pragma unroll
      for (int r = 0; r < 4; r++) {
        float v = acc[i][j][r] + bv;
        if (OUT_BF16)
          ((bf16*)Cout)[(size_t)(mr + r) * N + n] = (bf16)v;
        else
          ((float*)Cout)[(size_t)(mr + r) * N + n] = v;
      }
    }
  }
}

// --------------------------- RoPE + scatter ---------------------------------
// qkv16[S][3840] -> Q[h][s][96] (scaled by QSCALE, zero pad), K[h][s][96],
// VT[h][d][S].  Grid: H*48 blocks of 256 (64 s-rows each).
__global__ __launch_bounds__(256) void rope_scatter(
    const bf16* __restrict__ qkv, const float* __restrict__ rp,
    bf16* __restrict__ Qo, bf16* __restrict__ Ko, bf16* __restrict__ VTo) {
  __shared__ bf16 vl[80 * 72];  // [d][row] transpose buffer
  const int h = blockIdx.x / 48, st = blockIdx.x % 48;
  const int tid = threadIdx.x;
  const int r = tid >> 2, quad = tid & 3;
  const int s = st * 64 + r;
  const bf16* base = qkv + (size_t)s * NQKV;
  {  // V -> LDS transposed
    const bf16* vsrc = base + 2 * DIM + h * HD + quad * 20;
#pragma unroll
    for (int i = 0; i < 20; i++) vl[(quad * 20 + i) * 72 + r] = vsrc[i];
  }
  {  // rope: quads 0,1 -> Q halves; quads 2,3 -> K halves
    const int which = quad >> 1, half = quad & 1;
    const bf16* tsrc = base + which * DIM + h * HD;
    bf16* drow = (which ? Ko : Qo) + ((size_t)h * S + s) * DP;
    const float* rrow = rp + (size_t)s * (HD / 2);
    const float qsc = which ? 1.0f : QSCALE;
#pragma unroll
    for (int p = 0; p < 20; p++) {
      const int d = half * 20 + p;
      float sn, cs;
      __sincosf(rrow[d], &sn, &cs);
      float t1 = (float)tsrc[d], t2 = (float)tsrc[d + 40];
      drow[d] = (bf16)((t1 * cs - t2 * sn) * qsc);
      drow[d + 40] = (bf16)((t2 * cs + t1 * sn) * qsc);
    }
#pragma unroll
    for (int p = 0; p < 8; p++) drow[80 + half * 8 + p] = (bf16)0.f;
  }
  __syncthreads();
#pragma unroll
  for (int c = 0; c < 3; c++) {
    int ch = c * 256 + tid;
    if (ch < 640) {
      int d = ch >> 3, slot = ch & 7;
      *(bf16x8*)(VTo + (size_t)(h * HD + d) * S + st * 64 + slot * 8) =
          *(const bf16x8*)(vl + d * 72 + slot * 8);
    }
  }
}

// --------------------------- flash attention --------------------------------
// Per block: (head h, 64 q-rows). 4 waves x 16 q-rows. Swapped QK^T so each
// lane owns exactly one q-row (col=lane&15 of C). exp2-domain softmax.
__global__ __launch_bounds__(256) void attn_kern(
    const bf16* __restrict__ Qg, const bf16* __restrict__ Kg,
    const bf16* __restrict__ Vg, const int* __restrict__ cu, int nseg,
    bf16* __restrict__ Out) {
  __shared__ bf16 Kl[64 * 128];   // [key][d], 256B rows, XOR-swizzled
  __shared__ bf16 Vl[80 * 64];    // [d][key], 128B rows, XOR-swizzled
  __shared__ bf16 Pl[4][16 * 64]; // per wave [q][key], 128B rows, swizzled
  const int tid = threadIdx.x, w = tid >> 6, lane = tid & 63;
  const int r15 = lane & 15, b4 = lane >> 4;
  const int h = blockIdx.x / 48, qt = blockIdx.x % 48;
  const int q = qt * 64 + w * 16 + r15;  // this lane's q row
  int sq = 0, eq = S, lo = 0, hi = S;
  {
    const int qlo = qt * 64, qhi = qt * 64 + 63;
#pragma unroll
    for (int i = 0; i < 8; i++) {
      if (i >= nseg) break;
      int a = cu[i], b = cu[i + 1];
      if (q >= a && q < b) { sq = a; eq = b; }
      if (qlo >= a && qlo < b) lo = a;
      if (qhi >= a && qhi < b) hi = b;
    }
  }
  const int swz = (r15 & 7) << 4;
  bf16x8 qf[3];
  {
    const bf16* qrow = Qg + ((size_t)h * S + q) * DP + b4 * 8;
#pragma unroll
    for (int c = 0; c < 3; c++) qf[c] = *(const bf16x8*)(qrow + c * 32);
  }
  f32x4 o[5] = {};
  float m = -1e30f, l = 0.f;
  const bf16* Kbase = Kg + (size_t)h * S * DP;
  const bf16* Vbase = Vg + (size_t)h * HD * S;
  for (int k0 = lo & ~63; k0 < hi; k0 += 64) {
    __syncthreads();
    // stage K tile: 64 rows x 96 bf16 = 768 16B chunks
#pragma unroll
    for (int c = 0; c < 3; c++) {
      int ch = c * 256 + tid;
      int row = ch / 12, slot = ch % 12;
      bf16x8 kv = *(const bf16x8*)(Kbase + (size_t)(k0 + row) * DP + slot * 8);
      *(bf16x8*)((char*)Kl + ((row * 256 + slot * 16) ^ ((row & 7) << 4))) = kv;
    }
    // stage V^T tile: 80 rows x 64 bf16 = 640 chunks
#pragma unroll
    for (int c = 0; c < 3; c++) {
      int ch = c * 256 + tid;
      if (ch < 640) {
        int d = ch >> 3, slot = ch & 7;
        bf16x8 vv = *(const bf16x8*)(Vbase + (size_t)d * S + k0 + slot * 8);
        *(bf16x8*)((char*)Vl + ((d * 128 + slot * 16) ^ ((d & 7) << 4))) = vv;
      }
    }
    __syncthreads();
    // S^T = K * Q^T : per lane col = own q, rows = keys
    f32x4 st[4] = {};
#pragma unroll
    for (int g = 0; g < 4; g++)
#pragma unroll
      for (int c = 0; c < 3; c++) {
        bf16x8 kf = *(const bf16x8*)((const char*)Kl +
                                     (((g * 16 + r15) * 256 + c * 64 + b4 * 16) ^ swz));
        st[g] = __builtin_amdgcn_mfma_f32_16x16x32_bf16(kf, qf[c], st[g], 0, 0, 0);
      }
    // mask + online softmax (exp2 domain)
    float tm = -1e30f;
    float sv[16];
#pragma unroll
    for (int g = 0; g < 4; g++)
#pragma unroll
      for (int r = 0; r < 4; r++) {
        int key = k0 + g * 16 + b4 * 4 + r;
        float sc = (key >= sq && key < eq) ? st[g][r] : -1e30f;
        sv[g * 4 + r] = sc;
        tm = fmaxf(tm, sc);
      }
    tm = fmaxf(tm, __shfl_xor(tm, 16));
    tm = fmaxf(tm, __shfl_xor(tm, 32));
    const float mn = fmaxf(m, tm);
    const float alpha = __builtin_amdgcn_exp2f(m - mn);
    float rs = 0.f;
#pragma unroll
    for (int g = 0; g < 4; g++) {
      bf16x4 pp;
#pragma unroll
      for (int r = 0; r < 4; r++) {
        float p = __builtin_amdgcn_exp2f(sv[g * 4 + r] - mn);
        rs += p;
        pp[r] = (bf16)p;
      }
      *(bf16x4*)((char*)Pl[w] + ((r15 * 128 + g * 32 + b4 * 8) ^ swz)) = pp;
    }
    rs += __shfl_xor(rs, 16);
    rs += __shfl_xor(rs, 32);
    m = mn;
    l = l * alpha + rs;
#pragma unroll
    for (int dg = 0; dg < 5; dg++) o[dg] *= alpha;
    // O^T += V^T * P^T
#pragma unroll
    for (int dg = 0; dg < 5; dg++)
#pragma unroll
      for (int c = 0; c < 2; c++) {
        bf16x8 vf = *(const bf16x8*)((const char*)Vl +
                                     (((dg * 16 + r15) * 128 + c * 64 + b4 * 16) ^ swz));
        bf16x8 pf = *(const bf16x8*)((const char*)Pl[w] +
                                     ((r15 * 128 + c * 64 + b4 * 16) ^ swz));
        o[dg] = __builtin_amdgcn_mfma_f32_16x16x32_bf16(vf, pf, o[dg], 0, 0, 0);
      }
  }
  const float inv = 1.f / l;
  bf16* orow = Out + (size_t)q * DIM + h * HD + b4 * 4;
#pragma unroll
  for (int dg = 0; dg < 5; dg++) {
    bf16x4 ov = {(bf16)(o[dg][0] * inv), (bf16)(o[dg][1] * inv),
                 (bf16)(o[dg][2] * inv), (bf16)(o[dg][3] * inv)};
    *(bf16x4*)(orow + dg * 16) = ov;
  }
}

// --------------------------- launch -----------------------------------------
extern "C" void kernel_launch(void* const* d_in, const int* in_sizes, int n_in,
                              void* d_out, int out_size, void* d_ws,
                              size_t ws_size, hipStream_t stream) {
  const float* x = (const float*)d_in[0];
  const int* cu = (const int*)d_in[1];
  const float* rope = (const float*)d_in[2];
  const float* w_qkv = (const float*)d_in[3];
  const float* b_qkv = (const float*)d_in[4];
  const float* w_proj = (const float*)d_in[5];
  const float* b_proj = (const float*)d_in[6];
  const int nseg = in_sizes[1] - 1;

  bf16* x16 = (bf16*)d_ws;
  bf16* wq16 = x16 + (size_t)S * DIM;
  bf16* wp16 = wq16 + (size_t)NQKV * DIM;
  bf16* qkv16 = wp16 + (size_t)DIM * DIM;
  bf16* Qb = qkv16 + (size_t)S * NQKV;
  bf16* Kb = Qb + (size_t)H * S * DP;
  bf16* VTb = Kb + (size_t)H * S * DP;
  bf16* attn16 = VTb + (size_t)H * HD * S;

  cvt3<<<10240, 256, 0, stream>>>(x, w_qkv, w_proj, x16, wq16, wp16);
  gemm_bt<true><<<dim3(NQKV / 128, S / 128), 256, 0, stream>>>(
      x16, wq16, b_qkv, qkv16, S, NQKV, DIM);
  rope_scatter<<<H * 48, 256, 0, stream>>>(qkv16, rope, Qb, Kb, VTb);
  attn_kern<<<H * 48, 256, 0, stream>>>(Qb, Kb, VTb, cu, nseg, attn16);
  gemm_bt<false><<<dim3(DIM / 128, S / 128), 256, 0, stream>>>(
      attn16, wp16, b_proj, d_out, S, DIM, DIM);
}

// Round 2
// 133.747 us; speedup vs baseline: 1.0980x; 1.0980x over previous
//
#include <hip/hip_runtime.h>

// ---------------------------------------------------------------------------
// Attention block, MI355X bf16-MFMA implementation.  R2:
//  - GEMMs: stage-ahead double-buffered LDS (2-phase), XCD-aware block swizzle
//  - attn: K/V dbuf + async reg-staging (T14), defer-max (T13), mask elision,
//          setprio around MFMA clusters (T5)
// ---------------------------------------------------------------------------

typedef __bf16 bf16;
typedef __bf16 bf16x4 __attribute__((ext_vector_type(4)));
typedef __bf16 bf16x8 __attribute__((ext_vector_type(8)));
typedef float f32x4 __attribute__((ext_vector_type(4)));

constexpr int S = 3072;
constexpr int DIM = 1280;
constexpr int H = 16;
constexpr int HD = 80;
constexpr int DP = 96;          // padded head dim for QK (multiple of 32)
constexpr int NQKV = 3 * DIM;   // 3840

// log2(e) / sqrt(80): folded into Q so scores are in exp2 domain.
constexpr float QSCALE = 1.4426950408889634f / 8.94427190999916f;

__device__ __forceinline__ void gload_lds16(const void* g, void* l) {
  __builtin_amdgcn_global_load_lds(
      (const __attribute__((address_space(1))) void*)g,
      (__attribute__((address_space(3))) void*)l, 16, 0, 0);
}

// --------------------------- fp32 -> bf16 convert ---------------------------
constexpr long CN1 = (long)S * DIM;       // x
constexpr long CN2 = (long)NQKV * DIM;    // w_qkv

__global__ __launch_bounds__(256) void cvt3(
    const float* __restrict__ x, const float* __restrict__ wq,
    const float* __restrict__ wp, bf16* __restrict__ xo,
    bf16* __restrict__ wqo, bf16* __restrict__ wpo) {
  long i = ((long)blockIdx.x * 256 + threadIdx.x) * 4;
  const float* s;
  bf16* d;
  if (i < CN1) { s = x + i; d = xo + i; }
  else if (i < CN1 + CN2) { s = wq + (i - CN1); d = wqo + (i - CN1); }
  else { s = wp + (i - CN1 - CN2); d = wpo + (i - CN1 - CN2); }
  float4 v = *(const float4*)s;
  bf16x4 o = {(bf16)v.x, (bf16)v.y, (bf16)v.z, (bf16)v.w};
  *(bf16x4*)d = o;
}

// --------------------------- GEMM (A row-major, B^T rows) -------------------
// C[m][n] = sum_k A[m][k]*B[n][k] + bias[n].  128x128 tile, BK=32, 4 waves,
// double-buffered stage-ahead pipeline, XCD-swizzled block mapping.
template <bool OUT_BF16>
__global__ __launch_bounds__(256) void gemm_bt(
    const bf16* __restrict__ A, const bf16* __restrict__ B,
    const float* __restrict__ bias, void* __restrict__ Cout, int M, int N,
    int K) {
  __shared__ bf16 Al[2][128 * 32];
  __shared__ bf16 Bl[2][128 * 32];
  const int tid = threadIdx.x;
  const int w = tid >> 6, lane = tid & 63;
  const int r15 = lane & 15, b4 = lane >> 4;
  // XCD-aware swizzle: grid sizes here are always multiples of 8.
  const int nwg = gridDim.x * gridDim.y;
  const int orig = blockIdx.y * gridDim.x + blockIdx.x;
  const int swzid = (orig & 7) * (nwg >> 3) + (orig >> 3);
  const int bx = swzid % gridDim.x, by = swzid / gridDim.x;
  const int m0 = by * 128, n0 = bx * 128;
  const int wm = (w >> 1) * 64, wn = (w & 1) * 64;
  f32x4 acc[4][4] = {};
  const int row0 = tid >> 2, ko0 = (tid & 3) * 8;
  const bf16* Ar0 = A + (size_t)(m0 + row0) * K + ko0;
  const bf16* Ar1 = A + (size_t)(m0 + row0 + 64) * K + ko0;
  const bf16* Br0 = B + (size_t)(n0 + row0) * K + ko0;
  const bf16* Br1 = B + (size_t)(n0 + row0 + 64) * K + ko0;

  auto stage = [&](int buf, int k0) {
    char* la = (char*)Al[buf] + w * 1024;
    char* lb = (char*)Bl[buf] + w * 1024;
    gload_lds16(Ar0 + k0, la);
    gload_lds16(Ar1 + k0, la + 4096);
    gload_lds16(Br0 + k0, lb);
    gload_lds16(Br1 + k0, lb + 4096);
  };

  stage(0, 0);
  int cur = 0;
  for (int k0 = 0; k0 < K; k0 += 32) {
    __syncthreads();  // drains prev stage's vmcnt; protects buf reuse
    if (k0 + 32 < K) stage(cur ^ 1, k0 + 32);
    bf16x8 af[4], bfr[4];
#pragma unroll
    for (int i = 0; i < 4; i++) {
      af[i] = *(const bf16x8*)((const char*)Al[cur] + (wm + i * 16 + r15) * 64 + b4 * 16);
      bfr[i] = *(const bf16x8*)((const char*)Bl[cur] + (wn + i * 16 + r15) * 64 + b4 * 16);
    }
#pragma unroll
    for (int i = 0; i < 4; i++)
#pragma unroll
      for (int j = 0; j < 4; j++)
        acc[i][j] = __builtin_amdgcn_mfma_f32_16x16x32_bf16(af[i], bfr[j], acc[i][j], 0, 0, 0);
    cur ^= 1;
  }
#pragma unroll
  for (int j = 0; j < 4; j++) {
    const int n = n0 + wn + j * 16 + r15;
    const float bv = bias[n];
#pragma unroll
    for (int i = 0; i < 4; i++) {
      const int mr = m0 + wm + i * 16 + b4 * 4;
#pragma unroll
      for (int r = 0; r < 4; r++) {
        float v = acc[i][j][r] + bv;
        if (OUT_BF16)
          ((bf16*)Cout)[(size_t)(mr + r) * N + n] = (bf16)v;
        else
          ((float*)Cout)[(size_t)(mr + r) * N + n] = v;
      }
    }
  }
}

// --------------------------- RoPE + scatter ---------------------------------
__global__ __launch_bounds__(256) void rope_scatter(
    const bf16* __restrict__ qkv, const float* __restrict__ rp,
    bf16* __restrict__ Qo, bf16* __restrict__ Ko, bf16* __restrict__ VTo) {
  __shared__ bf16 vl[80 * 72];  // [d][row] transpose buffer
  const int h = blockIdx.x / 48, st = blockIdx.x % 48;
  const int tid = threadIdx.x;
  const int r = tid >> 2, quad = tid & 3;
  const int s = st * 64 + r;
  const bf16* base = qkv + (size_t)s * NQKV;
  {  // V -> LDS transposed
    const bf16* vsrc = base + 2 * DIM + h * HD + quad * 20;
#pragma unroll
    for (int i = 0; i < 20; i++) vl[(quad * 20 + i) * 72 + r] = vsrc[i];
  }
  {  // rope: quads 0,1 -> Q halves; quads 2,3 -> K halves
    const int which = quad >> 1, half = quad & 1;
    const bf16* tsrc = base + which * DIM + h * HD;
    bf16* drow = (which ? Ko : Qo) + ((size_t)h * S + s) * DP;
    const float* rrow = rp + (size_t)s * (HD / 2);
    const float qsc = which ? 1.0f : QSCALE;
#pragma unroll
    for (int p = 0; p < 20; p++) {
      const int d = half * 20 + p;
      float sn, cs;
      __sincosf(rrow[d], &sn, &cs);
      float t1 = (float)tsrc[d], t2 = (float)tsrc[d + 40];
      drow[d] = (bf16)((t1 * cs - t2 * sn) * qsc);
      drow[d + 40] = (bf16)((t2 * cs + t1 * sn) * qsc);
    }
#pragma unroll
    for (int p = 0; p < 8; p++) drow[80 + half * 8 + p] = (bf16)0.f;
  }
  __syncthreads();
#pragma unroll
  for (int c = 0; c < 3; c++) {
    int ch = c * 256 + tid;
    if (ch < 640) {
      int d = ch >> 3, slot = ch & 7;
      *(bf16x8*)(VTo + (size_t)(h * HD + d) * S + st * 64 + slot * 8) =
          *(const bf16x8*)(vl + d * 72 + slot * 8);
    }
  }
}

// --------------------------- flash attention --------------------------------
// Per block: (head h, 64 q-rows). 4 waves x 16 q-rows. Swapped QK^T so each
// lane owns one q-row. exp2-domain online softmax, defer-max, K/V dbuf with
// async reg-staging.
__global__ __launch_bounds__(256) void attn_kern(
    const bf16* __restrict__ Qg, const bf16* __restrict__ Kg,
    const bf16* __restrict__ Vg, const int* __restrict__ cu, int nseg,
    bf16* __restrict__ Out) {
  __shared__ bf16 Kl[2][64 * 128];   // [key][d], 256B rows, XOR-swizzled
  __shared__ bf16 Vl[2][80 * 64];    // [d][key], 128B rows, XOR-swizzled
  __shared__ bf16 Pl[4][16 * 64];    // per wave [q][key], swizzled
  const int tid = threadIdx.x, w = tid >> 6, lane = tid & 63;
  const int r15 = lane & 15, b4 = lane >> 4;
  const int nwg = gridDim.x;  // 768, multiple of 8
  const int orig = blockIdx.x;
  const int swzb = (orig & 7) * (nwg >> 3) + (orig >> 3);
  const int h = swzb / 48, qt = swzb % 48;
  const int q = qt * 64 + w * 16 + r15;
  int sq = 0, eq = S, lo = 0, hi = S;
  {
    const int qlo = qt * 64, qhi = qt * 64 + 63;
#pragma unroll
    for (int i = 0; i < 8; i++) {
      if (i >= nseg) break;
      int a = cu[i], b = cu[i + 1];
      if (q >= a && q < b) { sq = a; eq = b; }
      if (qlo >= a && qlo < b) lo = a;
      if (qhi >= a && qhi < b) hi = b;
    }
  }
  const int swz = (r15 & 7) << 4;
  bf16x8 qf[3];
  {
    const bf16* qrow = Qg + ((size_t)h * S + q) * DP + b4 * 8;
#pragma unroll
    for (int c = 0; c < 3; c++) qf[c] = *(const bf16x8*)(qrow + c * 32);
  }
  f32x4 o[5] = {};
  float m = -1e30f, l = 0.f;
  const bf16* Kbase = Kg + (size_t)h * S * DP;
  const bf16* Vbase = Vg + (size_t)h * HD * S;

  // staging geometry (per-thread constants)
  int krow[3], kslot[3], vd[3], vslot[3];
#pragma unroll
  for (int c = 0; c < 3; c++) {
    int ch = c * 256 + tid;
    krow[c] = ch / 12; kslot[c] = ch % 12;
    vd[c] = ch >> 3;   vslot[c] = ch & 7;
  }
  bf16x8 kreg[3], vreg[3];

  auto load_stage = [&](int k0) {
#pragma unroll
    for (int c = 0; c < 3; c++)
      kreg[c] = *(const bf16x8*)(Kbase + (size_t)(k0 + krow[c]) * DP + kslot[c] * 8);
#pragma unroll
    for (int c = 0; c < 3; c++)
      if (c < 2 || tid < 128)
        vreg[c] = *(const bf16x8*)(Vbase + (size_t)vd[c] * S + k0 + vslot[c] * 8);
  };
  auto write_stage = [&](int buf) {
#pragma unroll
    for (int c = 0; c < 3; c++)
      *(bf16x8*)((char*)Kl[buf] +
                 ((krow[c] * 256 + kslot[c] * 16) ^ ((krow[c] & 7) << 4))) = kreg[c];
#pragma unroll
    for (int c = 0; c < 3; c++)
      if (c < 2 || tid < 128)
        *(bf16x8*)((char*)Vl[buf] +
                   ((vd[c] * 128 + vslot[c] * 16) ^ ((vd[c] & 7) << 4))) = vreg[c];
  };

  const int k0start = lo & ~63;
  load_stage(k0start);
  write_stage(0);
  __syncthreads();
  int cur = 0;
  for (int k0 = k0start; k0 < hi; k0 += 64) {
    const bool more = (k0 + 64 < hi);
    if (more) load_stage(k0 + 64);  // issue early; latency hides under compute
    // ---- S^T = K * Q^T ----
    f32x4 st[4] = {};
    __builtin_amdgcn_s_setprio(1);
#pragma unroll
    for (int g = 0; g < 4; g++)
#pragma unroll
      for (int c = 0; c < 3; c++) {
        bf16x8 kf = *(const bf16x8*)((const char*)Kl[cur] +
                                     (((g * 16 + r15) * 256 + c * 64 + b4 * 16) ^ swz));
        st[g] = __builtin_amdgcn_mfma_f32_16x16x32_bf16(kf, qf[c], st[g], 0, 0, 0);
      }
    __builtin_amdgcn_s_setprio(0);
    // ---- mask (elided when tile fully in-segment) + online softmax ----
    float sv[16];
    float tm = -3e38f;
    if (k0 >= sq && k0 + 63 < eq) {
#pragma unroll
      for (int g = 0; g < 4; g++)
#pragma unroll
        for (int r = 0; r < 4; r++) {
          sv[g * 4 + r] = st[g][r];
          tm = fmaxf(tm, st[g][r]);
        }
    } else {
#pragma unroll
      for (int g = 0; g < 4; g++)
#pragma unroll
        for (int r = 0; r < 4; r++) {
          int key = k0 + g * 16 + b4 * 4 + r;
          float sc = (key >= sq && key < eq) ? st[g][r] : -1e30f;
          sv[g * 4 + r] = sc;
          tm = fmaxf(tm, sc);
        }
    }
    tm = fmaxf(tm, __shfl_xor(tm, 16));
    tm = fmaxf(tm, __shfl_xor(tm, 32));
    if (!__all(tm <= m + 8.f)) {  // defer-max: skip rescale for small growth
      const float mn = fmaxf(m, tm);
      const float alpha = __builtin_amdgcn_exp2f(m - mn);
#pragma unroll
      for (int dg = 0; dg < 5; dg++) o[dg] *= alpha;
      l *= alpha;
      m = mn;
    }
    float rs = 0.f;
#pragma unroll
    for (int g = 0; g < 4; g++) {
      bf16x4 pp;
#pragma unroll
      for (int r = 0; r < 4; r++) {
        float p = __builtin_amdgcn_exp2f(sv[g * 4 + r] - m);
        rs += p;
        pp[r] = (bf16)p;
      }
      *(bf16x4*)((char*)Pl[w] + ((r15 * 128 + g * 32 + b4 * 8) ^ swz)) = pp;
    }
    rs += __shfl_xor(rs, 16);
    rs += __shfl_xor(rs, 32);
    l += rs;
    // ---- O^T += V^T * P^T ----
    __builtin_amdgcn_s_setprio(1);
#pragma unroll
    for (int dg = 0; dg < 5; dg++)
#pragma unroll
      for (int c = 0; c < 2; c++) {
        bf16x8 vf = *(const bf16x8*)((const char*)Vl[cur] +
                                     (((dg * 16 + r15) * 128 + c * 64 + b4 * 16) ^ swz));
        bf16x8 pf = *(const bf16x8*)((const char*)Pl[w] +
                                     ((r15 * 128 + c * 64 + b4 * 16) ^ swz));
        o[dg] = __builtin_amdgcn_mfma_f32_16x16x32_bf16(vf, pf, o[dg], 0, 0, 0);
      }
    __builtin_amdgcn_s_setprio(0);
    if (more) write_stage(cur ^ 1);  // waits vmcnt, lands next tile
    __syncthreads();
    cur ^= 1;
  }
  const float inv = 1.f / l;
  bf16* orow = Out + (size_t)q * DIM + h * HD + b4 * 4;
#pragma unroll
  for (int dg = 0; dg < 5; dg++) {
    bf16x4 ov = {(bf16)(o[dg][0] * inv), (bf16)(o[dg][1] * inv),
                 (bf16)(o[dg][2] * inv), (bf16)(o[dg][3] * inv)};
    *(bf16x4*)(orow + dg * 16) = ov;
  }
}

// --------------------------- launch -----------------------------------------
extern "C" void kernel_launch(void* const* d_in, const int* in_sizes, int n_in,
                              void* d_out, int out_size, void* d_ws,
                              size_t ws_size, hipStream_t stream) {
  const float* x = (const float*)d_in[0];
  const int* cu = (const int*)d_in[1];
  const float* rope = (const float*)d_in[2];
  const float* w_qkv = (const float*)d_in[3];
  const float* b_qkv = (const float*)d_in[4];
  const float* w_proj = (const float*)d_in[5];
  const float* b_proj = (const float*)d_in[6];
  const int nseg = in_sizes[1] - 1;

  bf16* x16 = (bf16*)d_ws;
  bf16* wq16 = x16 + (size_t)S * DIM;
  bf16* wp16 = wq16 + (size_t)NQKV * DIM;
  bf16* qkv16 = wp16 + (size_t)DIM * DIM;
  bf16* Qb = qkv16 + (size_t)S * NQKV;
  bf16* Kb = Qb + (size_t)H * S * DP;
  bf16* VTb = Kb + (size_t)H * S * DP;
  bf16* attn16 = VTb + (size_t)H * HD * S;

  cvt3<<<10240, 256, 0, stream>>>(x, w_qkv, w_proj, x16, wq16, wp16);
  gemm_bt<true><<<dim3(NQKV / 128, S / 128), 256, 0, stream>>>(
      x16, wq16, b_qkv, qkv16, S, NQKV, DIM);
  rope_scatter<<<H * 48, 256, 0, stream>>>(qkv16, rope, Qb, Kb, VTb);
  attn_kern<<<H * 48, 256, 0, stream>>>(Qb, Kb, VTb, cu, nseg, attn16);
  gemm_bt<false><<<dim3(DIM / 128, S / 128), 256, 0, stream>>>(
      attn16, wp16, b_proj, d_out, S, DIM, DIM);
}

// Round 3
// 132.454 us; speedup vs baseline: 1.1087x; 1.0098x over previous
//
#include <hip/hip_runtime.h>

// ---------------------------------------------------------------------------
// Attention block, MI355X bf16-MFMA implementation.  R3:
//  - QKV GEMM: 256x256 8-wave, 4-slot ring (BK=32), counted vmcnt(8) pipeline
//    (T3+T4), XOR-swizzled LDS (T2-equivalent), setprio (T5), XCD swizzle.
//  - rope_scatter: fully vectorized bf16x8 loads/stores.
//  - attn / cvt3 / proj GEMM unchanged from R2 (isolation).
// ---------------------------------------------------------------------------

typedef __bf16 bf16;
typedef __bf16 bf16x4 __attribute__((ext_vector_type(4)));
typedef __bf16 bf16x8 __attribute__((ext_vector_type(8)));
typedef float f32x4 __attribute__((ext_vector_type(4)));

constexpr int S = 3072;
constexpr int DIM = 1280;
constexpr int H = 16;
constexpr int HD = 80;
constexpr int DP = 96;          // padded head dim for QK (multiple of 32)
constexpr int NQKV = 3 * DIM;   // 3840

// log2(e) / sqrt(80): folded into Q so scores are in exp2 domain.
constexpr float QSCALE = 1.4426950408889634f / 8.94427190999916f;

__device__ __forceinline__ void gload_lds16(const void* g, void* l) {
  __builtin_amdgcn_global_load_lds(
      (const __attribute__((address_space(1))) void*)g,
      (__attribute__((address_space(3))) void*)l, 16, 0, 0);
}

// --------------------------- fp32 -> bf16 convert ---------------------------
constexpr long CN1 = (long)S * DIM;       // x
constexpr long CN2 = (long)NQKV * DIM;    // w_qkv

__global__ __launch_bounds__(256) void cvt3(
    const float* __restrict__ x, const float* __restrict__ wq,
    const float* __restrict__ wp, bf16* __restrict__ xo,
    bf16* __restrict__ wqo, bf16* __restrict__ wpo) {
  long i = ((long)blockIdx.x * 256 + threadIdx.x) * 4;
  const float* s;
  bf16* d;
  if (i < CN1) { s = x + i; d = xo + i; }
  else if (i < CN1 + CN2) { s = wq + (i - CN1); d = wqo + (i - CN1); }
  else { s = wp + (i - CN1 - CN2); d = wpo + (i - CN1 - CN2); }
  float4 v = *(const float4*)s;
  bf16x4 o = {(bf16)v.x, (bf16)v.y, (bf16)v.z, (bf16)v.w};
  *(bf16x4*)d = o;
}

// --------------------------- 256^2 ring-buffer GEMM -------------------------
// C[m][n] = sum_k A[m][k]*B[n][k] + bias[n].  BM=BN=256, BK=32, 8 waves (2x4),
// 4-slot LDS ring (128 KB), stage slice kt+3 during phase kt, counted
// vmcnt(8) before each raw barrier (loads stay in flight across barriers).
// LDS swizzle: involution  a ^= ((a>>7)&7)<<4  (2-way max bank aliasing).
template <bool OUT_BF16>
__global__ __launch_bounds__(512, 2) void gemm256(
    const bf16* __restrict__ A, const bf16* __restrict__ B,
    const float* __restrict__ bias, void* __restrict__ Cout, int M, int N,
    int K) {
  extern __shared__ char lds[];  // 4 * (16KB A + 16KB B) = 128 KB
  const int tid = threadIdx.x;
  const int w = tid >> 6, lane = tid & 63;
  const int r15 = lane & 15, b4 = lane >> 4;
  const int wr = w >> 2, wc = w & 3;  // 2 x 4 wave grid
  // bijective XCD swizzle (nwg may not be divisible by 8)
  const int nwg = gridDim.x * gridDim.y;
  const int orig = blockIdx.y * gridDim.x + blockIdx.x;
  const int xcd = orig % 8, loc = orig / 8;
  const int qq = nwg / 8, rq = nwg % 8;
  const int swzid =
      (xcd < rq ? xcd * (qq + 1) : rq * (qq + 1) + (xcd - rq) * qq) + loc;
  const int n0 = (swzid % gridDim.x) * 256, m0 = (swzid / gridDim.x) * 256;
  // staging geometry: per thread 2 A-chunks + 2 B-chunks of 16B per slice.
  // linear in-slice LDS offset lin = (w*2+i)*1024 + lane*16; the global
  // source is pre-swizzled with the same involution the reads use.
  int aRow[2], aCol[2];
#pragma unroll
  for (int i = 0; i < 2; i++) {
    int lin = (w * 2 + i) * 1024 + lane * 16;
    int logi = lin ^ (((lin >> 7) & 7) << 4);
    aRow[i] = logi >> 6;
    aCol[i] = (logi & 63) >> 1;
  }
  const int NT = K / 32;
  auto stage = [&](int kt) {
    char* sa = lds + (kt & 3) * 32768;
    char* sb = sa + 16384;
    const int kb = kt * 32;
#pragma unroll
    for (int i = 0; i < 2; i++) {
      const int lin = (w * 2 + i) * 1024 + lane * 16;
      gload_lds16(A + (size_t)(m0 + aRow[i]) * K + kb + aCol[i], sa + lin);
      gload_lds16(B + (size_t)(n0 + aRow[i]) * K + kb + aCol[i], sb + lin);
    }
  };
  f32x4 acc[8][4] = {};
  stage(0); stage(1); stage(2);
  asm volatile("s_waitcnt vmcnt(8)" ::: "memory");  // slice 0 landed
  __builtin_amdgcn_s_barrier();
  for (int kt = 0; kt < NT; ++kt) {
    const char* As = lds + (kt & 3) * 32768;
    const char* Bs = As + 16384;
    if (kt + 3 < NT) stage(kt + 3);  // targets slot untouched for 3 phases
    bf16x8 af[8], bfr[4];
#pragma unroll
    for (int i = 0; i < 8; i++) {
      int a = (wr * 128 + i * 16 + r15) * 64 + b4 * 16;
      a ^= ((a >> 7) & 7) << 4;
      af[i] = *(const bf16x8*)(As + a);
    }
#pragma unroll
    for (int j = 0; j < 4; j++) {
      int a = (wc * 64 + j * 16 + r15) * 64 + b4 * 16;
      a ^= ((a >> 7) & 7) << 4;
      bfr[j] = *(const bf16x8*)(Bs + a);
    }
    __builtin_amdgcn_s_setprio(1);
#pragma unroll
    for (int i = 0; i < 8; i++)
#pragma unroll
      for (int j = 0; j < 4; j++)
        acc[i][j] = __builtin_amdgcn_mfma_f32_16x16x32_bf16(af[i], bfr[j],
                                                            acc[i][j], 0, 0, 0);
    __builtin_amdgcn_s_setprio(0);
    // ensure slice kt+1 landed before next phase reads it; keep the rest
    // (up to 2 slices = 8 loads) in flight across the barrier.
    const int rem = NT - 2 - kt;
    if (rem >= 2)      asm volatile("s_waitcnt vmcnt(8)" ::: "memory");
    else if (rem == 1) asm volatile("s_waitcnt vmcnt(4)" ::: "memory");
    else if (rem == 0) asm volatile("s_waitcnt vmcnt(0)" ::: "memory");
    else               asm volatile("" ::: "memory");
    __builtin_amdgcn_s_barrier();
  }
#pragma unroll
  for (int j = 0; j < 4; j++) {
    const int n = n0 + wc * 64 + j * 16 + r15;
    const float bv = bias[n];
#pragma unroll
    for (int i = 0; i < 8; i++) {
      const int mr = m0 + wr * 128 + i * 16 + b4 * 4;
#pragma unroll
      for (int r = 0; r < 4; r++) {
        float v = acc[i][j][r] + bv;
        if (OUT_BF16)
          ((bf16*)Cout)[(size_t)(mr + r) * N + n] = (bf16)v;
        else
          ((float*)Cout)[(size_t)(mr + r) * N + n] = v;
      }
    }
  }
}

// --------------------------- 128^2 2-phase GEMM (proj) ----------------------
template <bool OUT_BF16>
__global__ __launch_bounds__(256) void gemm_bt(
    const bf16* __restrict__ A, const bf16* __restrict__ B,
    const float* __restrict__ bias, void* __restrict__ Cout, int M, int N,
    int K) {
  __shared__ bf16 Al[2][128 * 32];
  __shared__ bf16 Bl[2][128 * 32];
  const int tid = threadIdx.x;
  const int w = tid >> 6, lane = tid & 63;
  const int r15 = lane & 15, b4 = lane >> 4;
  const int nwg = gridDim.x * gridDim.y;
  const int orig = blockIdx.y * gridDim.x + blockIdx.x;
  const int swzid = (orig & 7) * (nwg >> 3) + (orig >> 3);
  const int bx = swzid % gridDim.x, by = swzid / gridDim.x;
  const int m0 = by * 128, n0 = bx * 128;
  const int wm = (w >> 1) * 64, wn = (w & 1) * 64;
  f32x4 acc[4][4] = {};
  const int row0 = tid >> 2, ko0 = (tid & 3) * 8;
  const bf16* Ar0 = A + (size_t)(m0 + row0) * K + ko0;
  const bf16* Ar1 = A + (size_t)(m0 + row0 + 64) * K + ko0;
  const bf16* Br0 = B + (size_t)(n0 + row0) * K + ko0;
  const bf16* Br1 = B + (size_t)(n0 + row0 + 64) * K + ko0;

  auto stage = [&](int buf, int k0) {
    char* la = (char*)Al[buf] + w * 1024;
    char* lb = (char*)Bl[buf] + w * 1024;
    gload_lds16(Ar0 + k0, la);
    gload_lds16(Ar1 + k0, la + 4096);
    gload_lds16(Br0 + k0, lb);
    gload_lds16(Br1 + k0, lb + 4096);
  };

  stage(0, 0);
  int cur = 0;
  for (int k0 = 0; k0 < K; k0 += 32) {
    __syncthreads();
    if (k0 + 32 < K) stage(cur ^ 1, k0 + 32);
    bf16x8 af[4], bfr[4];
#pragma unroll
    for (int i = 0; i < 4; i++) {
      af[i] = *(const bf16x8*)((const char*)Al[cur] + (wm + i * 16 + r15) * 64 + b4 * 16);
      bfr[i] = *(const bf16x8*)((const char*)Bl[cur] + (wn + i * 16 + r15) * 64 + b4 * 16);
    }
#pragma unroll
    for (int i = 0; i < 4; i++)
#pragma unroll
      for (int j = 0; j < 4; j++)
        acc[i][j] = __builtin_amdgcn_mfma_f32_16x16x32_bf16(af[i], bfr[j], acc[i][j], 0, 0, 0);
    cur ^= 1;
  }
#pragma unroll
  for (int j = 0; j < 4; j++) {
    const int n = n0 + wn + j * 16 + r15;
    const float bv = bias[n];
#pragma unroll
    for (int i = 0; i < 4; i++) {
      const int mr = m0 + wm + i * 16 + b4 * 4;
#pragma unroll
      for (int r = 0; r < 4; r++) {
        float v = acc[i][j][r] + bv;
        if (OUT_BF16)
          ((bf16*)Cout)[(size_t)(mr + r) * N + n] = (bf16)v;
        else
          ((float*)Cout)[(size_t)(mr + r) * N + n] = v;
      }
    }
  }
}

// --------------------------- RoPE + scatter (vectorized) --------------------
// qkv16[S][3840] -> Q[h][s][96] (QSCALE, zero pad), K[h][s][96], VT[h][d][S].
// Grid: H*48 blocks of 256 (64 s-rows each). All global traffic bf16x8.
__global__ __launch_bounds__(256) void rope_scatter(
    const bf16* __restrict__ qkv, const float* __restrict__ rp,
    bf16* __restrict__ Qo, bf16* __restrict__ Ko, bf16* __restrict__ VTo) {
  __shared__ bf16 vl[80][72];  // [d][row] transpose buffer (pad 72)
  const int h = blockIdx.x / 48, st = blockIdx.x % 48;
  const int tid = threadIdx.x;
  // ---- V: vector-load 8 dims x 1 row, scatter to LDS transposed ----
#pragma unroll
  for (int c = 0; c < 3; c++) {
    int ch = c * 256 + tid;
    if (ch < 640) {
      int row = ch / 10, ck = ch % 10;
      int s = st * 64 + row;
      bf16x8 v = *(const bf16x8*)(qkv + (size_t)s * NQKV + 2 * DIM + h * HD + ck * 8);
#pragma unroll
      for (int e = 0; e < 8; e++) vl[ck * 8 + e][row] = v[e];
    }
  }
  // ---- Q/K rope: task = (row, which, chunk-pair) ----
#pragma unroll
  for (int c = 0; c < 3; c++) {
    int ch = c * 256 + tid;
    if (ch < 640) {
      int row = ch / 10, t10 = ch % 10;
      int which = t10 >= 5 ? 1 : 0, cp = t10 % 5;
      int s = st * 64 + row;
      const bf16* src = qkv + (size_t)s * NQKV + which * DIM + h * HD;
      bf16x8 lo = *(const bf16x8*)(src + cp * 8);
      bf16x8 hi = *(const bf16x8*)(src + 40 + cp * 8);
      const float* rr = rp + (size_t)s * 40 + cp * 8;
      float4 a0 = *(const float4*)rr;
      float4 a1 = *(const float4*)(rr + 4);
      float ang[8] = {a0.x, a0.y, a0.z, a0.w, a1.x, a1.y, a1.z, a1.w};
      const float sc = which ? 1.0f : QSCALE;
      bf16x8 olo, ohi;
#pragma unroll
      for (int e = 0; e < 8; e++) {
        float sn, cs;
        __sincosf(ang[e], &sn, &cs);
        float t1 = (float)lo[e], t2 = (float)hi[e];
        olo[e] = (bf16)((t1 * cs - t2 * sn) * sc);
        ohi[e] = (bf16)((t2 * cs + t1 * sn) * sc);
      }
      bf16* dst = (which ? Ko : Qo) + ((size_t)h * S + s) * DP;
      *(bf16x8*)(dst + cp * 8) = olo;
      *(bf16x8*)(dst + 40 + cp * 8) = ohi;
    }
  }
  // ---- zero-pad cols [80,96) of Q and K ----
  {
    int row = tid >> 2, slot = tid & 3;
    int s = st * 64 + row;
    bf16* dst = ((slot >> 1) ? Ko : Qo) + ((size_t)h * S + s) * DP + 80 + (slot & 1) * 8;
    bf16x8 z = {};
    *(bf16x8*)dst = z;
  }
  __syncthreads();
  // ---- VT: vector rows out of LDS ----
#pragma unroll
  for (int c = 0; c < 3; c++) {
    int ch = c * 256 + tid;
    if (ch < 640) {
      int d = ch >> 3, slot = ch & 7;
      *(bf16x8*)(VTo + (size_t)(h * HD + d) * S + st * 64 + slot * 8) =
          *(const bf16x8*)(&vl[d][slot * 8]);
    }
  }
}

// --------------------------- flash attention --------------------------------
__global__ __launch_bounds__(256) void attn_kern(
    const bf16* __restrict__ Qg, const bf16* __restrict__ Kg,
    const bf16* __restrict__ Vg, const int* __restrict__ cu, int nseg,
    bf16* __restrict__ Out) {
  __shared__ bf16 Kl[2][64 * 128];   // [key][d], 256B rows, XOR-swizzled
  __shared__ bf16 Vl[2][80 * 64];    // [d][key], 128B rows, XOR-swizzled
  __shared__ bf16 Pl[4][16 * 64];    // per wave [q][key], swizzled
  const int tid = threadIdx.x, w = tid >> 6, lane = tid & 63;
  const int r15 = lane & 15, b4 = lane >> 4;
  const int nwg = gridDim.x;  // 768, multiple of 8
  const int orig = blockIdx.x;
  const int swzb = (orig & 7) * (nwg >> 3) + (orig >> 3);
  const int h = swzb / 48, qt = swzb % 48;
  const int q = qt * 64 + w * 16 + r15;
  int sq = 0, eq = S, lo = 0, hi = S;
  {
    const int qlo = qt * 64, qhi = qt * 64 + 63;
#pragma unroll
    for (int i = 0; i < 8; i++) {
      if (i >= nseg) break;
      int a = cu[i], b = cu[i + 1];
      if (q >= a && q < b) { sq = a; eq = b; }
      if (qlo >= a && qlo < b) lo = a;
      if (qhi >= a && qhi < b) hi = b;
    }
  }
  const int swz = (r15 & 7) << 4;
  bf16x8 qf[3];
  {
    const bf16* qrow = Qg + ((size_t)h * S + q) * DP + b4 * 8;
#pragma unroll
    for (int c = 0; c < 3; c++) qf[c] = *(const bf16x8*)(qrow + c * 32);
  }
  f32x4 o[5] = {};
  float m = -1e30f, l = 0.f;
  const bf16* Kbase = Kg + (size_t)h * S * DP;
  const bf16* Vbase = Vg + (size_t)h * HD * S;

  int krow[3], kslot[3], vd[3], vslot[3];
#pragma unroll
  for (int c = 0; c < 3; c++) {
    int ch = c * 256 + tid;
    krow[c] = ch / 12; kslot[c] = ch % 12;
    vd[c] = ch >> 3;   vslot[c] = ch & 7;
  }
  bf16x8 kreg[3], vreg[3];

  auto load_stage = [&](int k0) {
#pragma unroll
    for (int c = 0; c < 3; c++)
      kreg[c] = *(const bf16x8*)(Kbase + (size_t)(k0 + krow[c]) * DP + kslot[c] * 8);
#pragma unroll
    for (int c = 0; c < 3; c++)
      if (c < 2 || tid < 128)
        vreg[c] = *(const bf16x8*)(Vbase + (size_t)vd[c] * S + k0 + vslot[c] * 8);
  };
  auto write_stage = [&](int buf) {
#pragma unroll
    for (int c = 0; c < 3; c++)
      *(bf16x8*)((char*)Kl[buf] +
                 ((krow[c] * 256 + kslot[c] * 16) ^ ((krow[c] & 7) << 4))) = kreg[c];
#pragma unroll
    for (int c = 0; c < 3; c++)
      if (c < 2 || tid < 128)
        *(bf16x8*)((char*)Vl[buf] +
                   ((vd[c] * 128 + vslot[c] * 16) ^ ((vd[c] & 7) << 4))) = vreg[c];
  };

  const int k0start = lo & ~63;
  load_stage(k0start);
  write_stage(0);
  __syncthreads();
  int cur = 0;
  for (int k0 = k0start; k0 < hi; k0 += 64) {
    const bool more = (k0 + 64 < hi);
    if (more) load_stage(k0 + 64);
    f32x4 st[4] = {};
    __builtin_amdgcn_s_setprio(1);
#pragma unroll
    for (int g = 0; g < 4; g++)
#pragma unroll
      for (int c = 0; c < 3; c++) {
        bf16x8 kf = *(const bf16x8*)((const char*)Kl[cur] +
                                     (((g * 16 + r15) * 256 + c * 64 + b4 * 16) ^ swz));
        st[g] = __builtin_amdgcn_mfma_f32_16x16x32_bf16(kf, qf[c], st[g], 0, 0, 0);
      }
    __builtin_amdgcn_s_setprio(0);
    float sv[16];
    float tm = -3e38f;
    if (k0 >= sq && k0 + 63 < eq) {
#pragma unroll
      for (int g = 0; g < 4; g++)
#pragma unroll
        for (int r = 0; r < 4; r++) {
          sv[g * 4 + r] = st[g][r];
          tm = fmaxf(tm, st[g][r]);
        }
    } else {
#pragma unroll
      for (int g = 0; g < 4; g++)
#pragma unroll
        for (int r = 0; r < 4; r++) {
          int key = k0 + g * 16 + b4 * 4 + r;
          float sc = (key >= sq && key < eq) ? st[g][r] : -1e30f;
          sv[g * 4 + r] = sc;
          tm = fmaxf(tm, sc);
        }
    }
    tm = fmaxf(tm, __shfl_xor(tm, 16));
    tm = fmaxf(tm, __shfl_xor(tm, 32));
    if (!__all(tm <= m + 8.f)) {
      const float mn = fmaxf(m, tm);
      const float alpha = __builtin_amdgcn_exp2f(m - mn);
#pragma unroll
      for (int dg = 0; dg < 5; dg++) o[dg] *= alpha;
      l *= alpha;
      m = mn;
    }
    float rs = 0.f;
#pragma unroll
    for (int g = 0; g < 4; g++) {
      bf16x4 pp;
#pragma unroll
      for (int r = 0; r < 4; r++) {
        float p = __builtin_amdgcn_exp2f(sv[g * 4 + r] - m);
        rs += p;
        pp[r] = (bf16)p;
      }
      *(bf16x4*)((char*)Pl[w] + ((r15 * 128 + g * 32 + b4 * 8) ^ swz)) = pp;
    }
    rs += __shfl_xor(rs, 16);
    rs += __shfl_xor(rs, 32);
    l += rs;
    __builtin_amdgcn_s_setprio(1);
#pragma unroll
    for (int dg = 0; dg < 5; dg++)
#pragma unroll
      for (int c = 0; c < 2; c++) {
        bf16x8 vf = *(const bf16x8*)((const char*)Vl[cur] +
                                     (((dg * 16 + r15) * 128 + c * 64 + b4 * 16) ^ swz));
        bf16x8 pf = *(const bf16x8*)((const char*)Pl[w] +
                                     ((r15 * 128 + c * 64 + b4 * 16) ^ swz));
        o[dg] = __builtin_amdgcn_mfma_f32_16x16x32_bf16(vf, pf, o[dg], 0, 0, 0);
      }
    __builtin_amdgcn_s_setprio(0);
    if (more) write_stage(cur ^ 1);
    __syncthreads();
    cur ^= 1;
  }
  const float inv = 1.f / l;
  bf16* orow = Out + (size_t)q * DIM + h * HD + b4 * 4;
#pragma unroll
  for (int dg = 0; dg < 5; dg++) {
    bf16x4 ov = {(bf16)(o[dg][0] * inv), (bf16)(o[dg][1] * inv),
                 (bf16)(o[dg][2] * inv), (bf16)(o[dg][3] * inv)};
    *(bf16x4*)(orow + dg * 16) = ov;
  }
}

// --------------------------- launch -----------------------------------------
extern "C" void kernel_launch(void* const* d_in, const int* in_sizes, int n_in,
                              void* d_out, int out_size, void* d_ws,
                              size_t ws_size, hipStream_t stream) {
  const float* x = (const float*)d_in[0];
  const int* cu = (const int*)d_in[1];
  const float* rope = (const float*)d_in[2];
  const float* w_qkv = (const float*)d_in[3];
  const float* b_qkv = (const float*)d_in[4];
  const float* w_proj = (const float*)d_in[5];
  const float* b_proj = (const float*)d_in[6];
  const int nseg = in_sizes[1] - 1;

  bf16* x16 = (bf16*)d_ws;
  bf16* wq16 = x16 + (size_t)S * DIM;
  bf16* wp16 = wq16 + (size_t)NQKV * DIM;
  bf16* qkv16 = wp16 + (size_t)DIM * DIM;
  bf16* Qb = qkv16 + (size_t)S * NQKV;
  bf16* Kb = Qb + (size_t)H * S * DP;
  bf16* VTb = Kb + (size_t)H * S * DP;
  bf16* attn16 = VTb + (size_t)H * HD * S;

  cvt3<<<10240, 256, 0, stream>>>(x, w_qkv, w_proj, x16, wq16, wp16);
  gemm256<true><<<dim3(NQKV / 256, S / 256), 512, 131072, stream>>>(
      x16, wq16, b_qkv, qkv16, S, NQKV, DIM);
  rope_scatter<<<H * 48, 256, 0, stream>>>(qkv16, rope, Qb, Kb, VTb);
  attn_kern<<<H * 48, 256, 0, stream>>>(Qb, Kb, VTb, cu, nseg, attn16);
  gemm_bt<false><<<dim3(DIM / 128, S / 128), 256, 0, stream>>>(
      attn16, wp16, b_proj, d_out, S, DIM, DIM);
}